// Round 13
// baseline (1211.746 us; speedup 1.0000x reference)
//
#include <hip/hip_runtime.h>
#include <stdint.h>

#define NB 16
#define NS 256
#define NV 32000
#define NE 512
#define NH 1024
#define PAD_IDX 3

// workspace byte offsets
#define WS_XP    0L                 // f32 [4096][1024]   16,777,216 B
#define WS_HCH   16777216L          // bf16 [257][16][1024] 8,421,376 B
#define WS_WHO   25198592L          // bf16 [32000][1024] 65,536,000 B
#define WS_FLG   90734592L          // u32 allvis[260] + fin[64] + cnt
#define WS_NEED  90800384L

typedef __attribute__((ext_vector_type(8))) short bf16x8;
typedef __attribute__((ext_vector_type(4))) float f32x4;
typedef __attribute__((ext_vector_type(4))) uint32_t u32x4;

__device__ __forceinline__ uint16_t f2bf(float f){
  union { float f; uint32_t u; } v; v.f = f;
  return (uint16_t)((v.u + 0x7fffu + ((v.u >> 16) & 1u)) >> 16);  // RNE
}

__device__ __forceinline__ bf16x8 pack8(float4 a, float4 b){
  bf16x8 r;
  r[0]=(short)f2bf(a.x); r[1]=(short)f2bf(a.y); r[2]=(short)f2bf(a.z); r[3]=(short)f2bf(a.w);
  r[4]=(short)f2bf(b.x); r[5]=(short)f2bf(b.y); r[6]=(short)f2bf(b.z); r[7]=(short)f2bf(b.w);
  return r;
}

// device-coherent (L3) ops: bypass L1+L2
__device__ __forceinline__ u32x4 load_coh16(const void* p){
  u32x4 r;
  asm volatile("global_load_dwordx4 %0, %1, off sc0 sc1" : "=v"(r) : "v"(p) : "memory");
  return r;
}
__device__ __forceinline__ uint32_t load_coh4(const void* p){
  uint32_t r;
  asm volatile("global_load_dword %0, %1, off sc0 sc1" : "=v"(r) : "v"(p) : "memory");
  return r;
}
__device__ __forceinline__ void store_coh8(void* p, uint64_t v){
  asm volatile("global_store_dwordx2 %0, %1, off sc0 sc1" :: "v"(p), "v"(v) : "memory");
}
__device__ __forceinline__ void store_coh4(void* p, uint32_t v){
  asm volatile("global_store_dword %0, %1, off sc0 sc1" :: "v"(p), "v"(v) : "memory");
}
// streaming store: system-scope write-around + non-temporal -> keep L3 clean
__device__ __forceinline__ void store_nt4(void* p, float v){
  asm volatile("global_store_dword %0, %1, off sc1 nt" :: "v"(p), "v"(v) : "memory");
}

__device__ __forceinline__ u32x4 umax4(u32x4 a, u32x4 b){
  u32x4 r;
  r[0] = a[0] > b[0] ? a[0] : b[0];
  r[1] = a[1] > b[1] ? a[1] : b[1];
  r[2] = a[2] > b[2] ? a[2] : b[2];
  r[3] = a[3] > b[3] ? a[3] : b[3];
  return r;
}

// clamped fast tanh; abs err ~1e-5, never NaN/inf (|out|<=1 -> bf16 never 0xFFFF)
__device__ __forceinline__ float tanh_fast(float x){
  x = fminf(fmaxf(x, -10.f), 10.f);
  float t = __builtin_amdgcn_exp2f(x * 2.885390081777927f);  // 2*log2(e)
  return (t - 1.0f) * __builtin_amdgcn_rcpf(t + 1.0f);
}

// ---- K0 merged prologue: [0,2048) init | [2048,18048) cvt | [18048,19072) xproj
__global__ __launch_bounds__(256) void k_pre(
    const float* __restrict__ hidden, uint16_t* __restrict__ hch,
    uint32_t* __restrict__ flg, const float* __restrict__ who,
    uint32_t* __restrict__ whodst, const int* __restrict__ ids,
    const float* __restrict__ tab, const float* __restrict__ wxh,
    const float* __restrict__ bxh, float* __restrict__ xp){
  int bid = blockIdx.x;
  int tid = threadIdx.x;

  if (bid < 2048){
    // sentinel-fill hchain slots 1..256, hidden -> slot 0, zero flags+counter
    long idx = (long)bid * 256 + tid;
    ((u32x4*)(hch + (long)NB * NH))[idx] = (u32x4){~0u, ~0u, ~0u, ~0u};
    if (idx < NB * NH) hch[idx] = f2bf(hidden[idx]);
    if (idx < 512) flg[idx] = 0u;                  // allvis[260]+fin[64]+cnt
    return;
  }
  if (bid < 18048){
    // Who_w f32 -> bf16
    long idx = (long)(bid - 2048) * 256 + tid;     // 4,096,000 threads, 8 f32 each
    const float4* p = (const float4*)who;
    float4 a = p[idx*2], b = p[idx*2+1];
    u32x4 d;
    d[0] = (uint32_t)f2bf(a.x) | ((uint32_t)f2bf(a.y) << 16);
    d[1] = (uint32_t)f2bf(a.z) | ((uint32_t)f2bf(a.w) << 16);
    d[2] = (uint32_t)f2bf(b.x) | ((uint32_t)f2bf(b.y) << 16);
    d[3] = (uint32_t)f2bf(b.z) | ((uint32_t)f2bf(b.w) << 16);
    ((u32x4*)whodst)[idx] = d;
    return;
  }
  {
    // xp[m][n] = sum_k emb(ids[m])[k] * Wxh[n][k] + b[n]
    int xb = bid - 18048;                 // 64 M-tiles x 16 N-tiles
    int tm = xb & 63, tn = xb >> 6;
    int Mb = tm * 64, Nb = tn * 64;
    int w = tid >> 6, l = tid & 63;
    int lr = l & 15, lk = l >> 4;

    int m = Mb + w*16 + lr;
    int id = ids[m];
    const float* arow = tab + (long)id * NE;
    bool pad = (id == PAD_IDX);

    f32x4 acc[4];
    #pragma unroll
    for (int j = 0; j < 4; ++j) acc[j] = (f32x4){0.f,0.f,0.f,0.f};

    for (int k0 = 0; k0 < NE; k0 += 32){
      int k = k0 + lk*8;
      bf16x8 af = (bf16x8){0,0,0,0,0,0,0,0};
      if (!pad){
        float4 a = *(const float4*)(arow + k);
        float4 b = *(const float4*)(arow + k + 4);
        af = pack8(a, b);
      }
      #pragma unroll
      for (int j = 0; j < 4; ++j){
        const float* brow = wxh + (long)(Nb + j*16 + lr) * NE + k;
        float4 x = *(const float4*)brow;
        float4 y = *(const float4*)(brow + 4);
        bf16x8 bf_ = pack8(x, y);
        acc[j] = __builtin_amdgcn_mfma_f32_16x16x32_bf16(af, bf_, acc[j], 0, 0, 0);
      }
    }
    #pragma unroll
    for (int j = 0; j < 4; ++j){
      int n = Nb + j*16 + lr;
      float bias = bxh[n];
      #pragma unroll
      for (int r = 0; r < 4; ++r){
        int row = Mb + w*16 + lk*4 + r;
        xp[(long)row * NH + n] = acc[j][r] + bias;
      }
    }
  }
}

// ---- K1 fused (R12 structure; GEMM now PERSISTENT via atomic tile counter).
// RNN (bids 0..63): 2 waves split-K, Whh halves in 64 VGPR; one sentinel
//   data-poll per step; LDS partial combine; write-through store of slot t+1.
//   Block 0 publishes allvis[t] after its post-poll barrier (its pass proves
//   slot t fully at L3). fin[role] certifies slot 256.
// GEMM (bids 64..447): 384 persistent workers; tile from atomic counter
//   (s-major order tile = tm*250+tn); gate allvis[tm*8+8] (one 4 B line) or
//   fin for the last s-group; reg-staged 128x128; out stored sc1 nt
//   (write-around L3 -> whobf stays resident; FETCH should collapse).
__global__ __launch_bounds__(256, 2) void k_fused(
    const float* __restrict__ whh, const float* __restrict__ xp,
    uint16_t* __restrict__ hch, const uint16_t* __restrict__ whobf,
    const float* __restrict__ whob, uint32_t* __restrict__ allvis,
    uint32_t* __restrict__ fin, uint32_t* __restrict__ cnt,
    float* __restrict__ out, float* __restrict__ hfin){
  __shared__ __align__(16) char smem[17*1024];
  __shared__ int tsh;
  const int bid = blockIdx.x;
  const int tid = threadIdx.x;

  if (bid < 64){
    // ================= RNN path (2 waves, split-K) =================
    if (tid >= 128) return;
    float*    accbuf = (float*)smem;                 // [2][64][4] f32, 2 KB
    uint16_t* hs2    = (uint16_t*)(smem + 2048);     // [2][256] bf16, 1 KB
    const int wv = tid >> 6;        // 0 or 1 (K-half)
    const int l  = tid & 63;
    const int j0 = bid * 16;
    const int lr = l & 15, lk = l >> 4;
    __builtin_amdgcn_s_setprio(2);

    // Whh fragments for this wave's K-half -> registers (64 VGPR)
    bf16x8 bfrag[16];
    #pragma unroll
    for (int kk = 0; kk < 16; ++kk){
      const float* s0 = whh + (long)(j0 + lr) * NH + (wv*16 + kk)*32 + lk*8;
      float4 a = *(const float4*)s0;
      float4 b = *(const float4*)(s0 + 4);
      bfrag[kk] = pack8(a, b);
    }

    float xpreg[4];
    if (wv == 0){
      #pragma unroll
      for (int r = 0; r < 4; ++r)
        xpreg[r] = xp[((long)(lk*4 + r) * NS + 0) * NH + j0 + lr];
    }

    const char* hbase = (const char*)hch;
    for (int t = 0; t < NS; ++t){
      const char* hsrc = hbase + (long)t * NB * NH * 2 + lr * 2048 + wv * 1024 + lk * 16;
      u32x4 hfrag[16];
      while (true){
        #pragma unroll
        for (int kk = 0; kk < 16; ++kk)
          hfrag[kk] = load_coh16(hsrc + kk * 64);
        asm volatile("s_waitcnt vmcnt(0)" ::: "memory");
        __builtin_amdgcn_sched_barrier(0);   // pin check AFTER waitcnt (rule #18)
        u32x4 m4 = hfrag[0];
        #pragma unroll
        for (int kk = 1; kk < 16; ++kk) m4 = umax4(m4, hfrag[kk]);
        uint32_t m01 = m4[0] > m4[1] ? m4[0] : m4[1];
        uint32_t m23 = m4[2] > m4[3] ? m4[2] : m4[3];
        uint32_t m = m01 > m23 ? m01 : m23;
        if (__all(m != 0xFFFFFFFFu)) break;
      }
      __builtin_amdgcn_sched_barrier(0);

      f32x4 a0 = (f32x4){0.f,0.f,0.f,0.f}, a1 = a0, a2 = a0, a3 = a0;
      #pragma unroll
      for (int kk = 0; kk < 16; kk += 4){
        a0 = __builtin_amdgcn_mfma_f32_16x16x32_bf16(*(const bf16x8*)&hfrag[kk  ], bfrag[kk  ], a0, 0, 0, 0);
        a1 = __builtin_amdgcn_mfma_f32_16x16x32_bf16(*(const bf16x8*)&hfrag[kk+1], bfrag[kk+1], a1, 0, 0, 0);
        a2 = __builtin_amdgcn_mfma_f32_16x16x32_bf16(*(const bf16x8*)&hfrag[kk+2], bfrag[kk+2], a2, 0, 0, 0);
        a3 = __builtin_amdgcn_mfma_f32_16x16x32_bf16(*(const bf16x8*)&hfrag[kk+3], bfrag[kk+3], a3, 0, 0, 0);
      }
      f32x4 acc = (a0 + a1) + (a2 + a3);

      if (wv == 1)
        *(f32x4*)&accbuf[((t & 1)*64 + l)*4] = acc;   // partial -> wave0
      __syncthreads();   // both waves' polls passed; slot t fully read

      if (wv == 0){
        if (bid == 0 && l == 0) store_coh4(allvis + t, 1u);
        f32x4 o = *(const f32x4*)&accbuf[((t & 1)*64 + l)*4];
        uint16_t* hb = hs2 + (t & 1)*256;
        #pragma unroll
        for (int r = 0; r < 4; ++r){
          int b = lk*4 + r;                           // C/D: row=(l>>4)*4+r, col=l&15
          float hv = tanh_fast(xpreg[r] + acc[r] + o[r]);
          hb[b*16 + lr] = f2bf(hv);
          if (t == NS-1) hfin[b*NH + j0 + lr] = hv;
        }
        asm volatile("s_waitcnt lgkmcnt(0)" ::: "memory");
        __builtin_amdgcn_sched_barrier(0);
        int rb = l >> 2, cc = l & 3;
        uint32_t w0 = *(const uint32_t*)&hb[rb*16 + cc*4];
        uint32_t w1 = *(const uint32_t*)&hb[rb*16 + cc*4 + 2];
        char* dst = (char*)hch + (long)(t+1) * NB * NH * 2 + rb * 2048 + j0*2 + cc*8;
        store_coh8(dst, ((uint64_t)w1 << 32) | (uint64_t)w0);
        if (t + 1 < NS){
          #pragma unroll
          for (int r = 0; r < 4; ++r)
            xpreg[r] = xp[((long)(lk*4 + r) * NS + (t+1)) * NH + j0 + lr];
        }
      }
    }
    if (wv == 0){
      asm volatile("s_waitcnt vmcnt(0)" ::: "memory");   // slot-256 stores acked
      if (l == 0) store_coh4(fin + bid, 1u);
    }
    return;
  }

  // ================= persistent logits workers =================
  uint16_t* As = (uint16_t*)smem;          // 8 KB
  uint16_t* Bs = (uint16_t*)(smem + 8192); // 8 KB
  int wv = tid >> 6, l = tid & 63;
  int wm = wv >> 1, wn = wv & 1;
  int lr = l & 15, lk = l >> 4;
  int r0 = tid >> 2, c0 = tid & 3;
  int r1 = r0 + 64;
  int da0 = r0*4 + (c0 ^ (r0 & 3));
  int da1 = r1*4 + (c0 ^ (r1 & 3));

  while (true){
    if (tid == 0)
      tsh = (int)__hip_atomic_fetch_add(cnt, 1u, __ATOMIC_RELAXED, __HIP_MEMORY_SCOPE_AGENT);
    __syncthreads();
    int tile = tsh;                        // barrier below (gate) precedes next write
    if (tile >= 8000) break;

    int tm = tile / 250;                   // s-group (8 steps per tile)
    int tn = tile % 250;
    int Mb = tm * 128, Nb = tn * 128;
    int hs = tm * 8 + 8;                   // highest needed slot

    if (hs < 256){                         // gate: ONE u32 (shared line)
      while (true){
        uint32_t f = load_coh4(allvis + hs);
        asm volatile("s_waitcnt vmcnt(0)" ::: "memory");
        __builtin_amdgcn_sched_barrier(0);
        if (__syncthreads_count(f == 0u) == 0) break;
        __builtin_amdgcn_s_sleep(16);
      }
    } else {                               // last s-group: 64 per-block finals
      const uint32_t* gp = fin + (tid & 63);
      while (true){
        uint32_t f = load_coh4(gp);
        asm volatile("s_waitcnt vmcnt(0)" ::: "memory");
        __builtin_amdgcn_sched_barrier(0);
        if (__syncthreads_count(f == 0u) == 0) break;
        __builtin_amdgcn_s_sleep(16);
      }
    }

    // s-major: A row m <-> hchain row m+16 (contiguous)
    const uint16_t* pa0 = hch + (long)(Mb + r0 + 16) * NH + c0*8;
    const uint16_t* pa1 = hch + (long)(Mb + r1 + 16) * NH + c0*8;
    const uint16_t* pb0 = whobf + (long)(Nb + r0) * NH + c0*8;
    const uint16_t* pb1 = whobf + (long)(Nb + r1) * NH + c0*8;

    u32x4 ra0 = *(const u32x4*)pa0;
    u32x4 ra1 = *(const u32x4*)pa1;
    u32x4 rb0 = *(const u32x4*)pb0;
    u32x4 rb1 = *(const u32x4*)pb1;

    f32x4 acc[4][4];
    #pragma unroll
    for (int i = 0; i < 4; ++i)
      #pragma unroll
      for (int jj = 0; jj < 4; ++jj) acc[i][jj] = (f32x4){0.f,0.f,0.f,0.f};

    for (int kt = 0; kt < 32; ++kt){
      ((u32x4*)As)[da0] = ra0;
      ((u32x4*)As)[da1] = ra1;
      ((u32x4*)Bs)[da0] = rb0;
      ((u32x4*)Bs)[da1] = rb1;
      __syncthreads();
      if (kt != 31){
        int off = (kt + 1) * 32;
        ra0 = *(const u32x4*)(pa0 + off);
        ra1 = *(const u32x4*)(pa1 + off);
        rb0 = *(const u32x4*)(pb0 + off);
        rb1 = *(const u32x4*)(pb1 + off);
      }
      bf16x8 af[4], bg_[4];
      #pragma unroll
      for (int i = 0; i < 4; ++i){
        int ra = wm*64 + i*16 + lr;
        int rb = wn*64 + i*16 + lr;
        af[i]  = *(const bf16x8*)&((const u32x4*)As)[ra*4 + (lk ^ (ra & 3))];
        bg_[i] = *(const bf16x8*)&((const u32x4*)Bs)[rb*4 + (lk ^ (rb & 3))];
      }
      #pragma unroll
      for (int i = 0; i < 4; ++i)
        #pragma unroll
        for (int jj = 0; jj < 4; ++jj)
          acc[i][jj] = __builtin_amdgcn_mfma_f32_16x16x32_bf16(af[i], bg_[jj], acc[i][jj], 0, 0, 0);
      __syncthreads();
    }

    #pragma unroll
    for (int jj = 0; jj < 4; ++jj){
      int col = Nb + wn*64 + jj*16 + lr;
      float bias = whob[col];
      #pragma unroll
      for (int i = 0; i < 4; ++i){
        #pragma unroll
        for (int rr = 0; rr < 4; ++rr){
          int m = Mb + wm*64 + i*16 + lk*4 + rr;      // m = s*16 + b
          long orow = (long)((m & 15) * 256 + (m >> 4));
          store_nt4(&out[orow * NV + col], acc[i][jj][rr] + bias);
        }
      }
    }
  }
}

extern "C" void kernel_launch(void* const* d_in, const int* in_sizes, int n_in,
                              void* d_out, int out_size, void* d_ws, size_t ws_size,
                              hipStream_t stream){
  (void)in_sizes; (void)n_in; (void)out_size;
  if (ws_size < (size_t)WS_NEED) return;   // insufficient scratch -> fail loudly

  const int*   ids    = (const int*)  d_in[0];
  const float* hidden = (const float*)d_in[1];
  const float* table  = (const float*)d_in[2];
  const float* wxh    = (const float*)d_in[3];
  const float* bxh    = (const float*)d_in[4];
  const float* whh    = (const float*)d_in[5];
  const float* who    = (const float*)d_in[6];
  const float* whob   = (const float*)d_in[7];

  char* ws = (char*)d_ws;
  float*    xp     = (float*)   (ws + WS_XP);
  uint16_t* hchain = (uint16_t*)(ws + WS_HCH);
  uint16_t* whobf  = (uint16_t*)(ws + WS_WHO);
  uint32_t* allvis = (uint32_t*)(ws + WS_FLG);     // [260]
  uint32_t* fin    = allvis + 260;                 // [64]
  uint32_t* cnt    = allvis + 324;                 // [1]
  float* out    = (float*)d_out;
  float* hfinal = out + (long)NB * NS * NV;   // 131,072,000

  k_pre  <<<19072, 256, 0, stream>>>(hidden, hchain, allvis, who,
                                     (uint32_t*)whobf, ids, table, wxh, bxh, xp);
  k_fused<<<448,   256, 0, stream>>>(whh, xp, hchain, whobf, whob,
                                     allvis, fin, cnt, out, hfinal);
}

// Round 14
// 1126.466 us; speedup vs baseline: 1.0757x; 1.0757x over previous
//
#include <hip/hip_runtime.h>
#include <stdint.h>

#define NB 16
#define NS 256
#define NV 32000
#define NE 512
#define NH 1024
#define PAD_IDX 3

// workspace byte offsets
#define WS_XP    0L                 // f32 [4096][1024]   16,777,216 B
#define WS_HCH   16777216L          // bf16 [257][16][1024] 8,421,376 B
#define WS_WHO   25198592L          // bf16 [32000][1024] 65,536,000 B
#define WS_FLG   90734592L          // u32 allvis[260] + fin[64]
#define WS_NEED  90800384L

typedef __attribute__((ext_vector_type(8))) short bf16x8;
typedef __attribute__((ext_vector_type(4))) float f32x4;
typedef __attribute__((ext_vector_type(4))) uint32_t u32x4;

__device__ __forceinline__ uint16_t f2bf(float f){
  union { float f; uint32_t u; } v; v.f = f;
  return (uint16_t)((v.u + 0x7fffu + ((v.u >> 16) & 1u)) >> 16);  // RNE
}

__device__ __forceinline__ bf16x8 pack8(float4 a, float4 b){
  bf16x8 r;
  r[0]=(short)f2bf(a.x); r[1]=(short)f2bf(a.y); r[2]=(short)f2bf(a.z); r[3]=(short)f2bf(a.w);
  r[4]=(short)f2bf(b.x); r[5]=(short)f2bf(b.y); r[6]=(short)f2bf(b.z); r[7]=(short)f2bf(b.w);
  return r;
}

// device-coherent (L3) ops: bypass L1+L2
__device__ __forceinline__ u32x4 load_coh16(const void* p){
  u32x4 r;
  asm volatile("global_load_dwordx4 %0, %1, off sc0 sc1" : "=v"(r) : "v"(p) : "memory");
  return r;
}
__device__ __forceinline__ uint32_t load_coh4(const void* p){
  uint32_t r;
  asm volatile("global_load_dword %0, %1, off sc0 sc1" : "=v"(r) : "v"(p) : "memory");
  return r;
}
__device__ __forceinline__ void store_coh8(void* p, uint64_t v){
  asm volatile("global_store_dwordx2 %0, %1, off sc0 sc1" :: "v"(p), "v"(v) : "memory");
}
__device__ __forceinline__ void store_coh4(void* p, uint32_t v){
  asm volatile("global_store_dword %0, %1, off sc0 sc1" :: "v"(p), "v"(v) : "memory");
}
// non-temporal store: don't pollute L3 with the 524 MB out stream
__device__ __forceinline__ void store_nt4(void* p, float v){
  asm volatile("global_store_dword %0, %1, off nt" :: "v"(p), "v"(v) : "memory");
}

__device__ __forceinline__ u32x4 umax4(u32x4 a, u32x4 b){
  u32x4 r;
  r[0] = a[0] > b[0] ? a[0] : b[0];
  r[1] = a[1] > b[1] ? a[1] : b[1];
  r[2] = a[2] > b[2] ? a[2] : b[2];
  r[3] = a[3] > b[3] ? a[3] : b[3];
  return r;
}

// clamped fast tanh; abs err ~1e-5, never NaN/inf (|out|<=1 -> bf16 never 0xFFFF)
__device__ __forceinline__ float tanh_fast(float x){
  x = fminf(fmaxf(x, -10.f), 10.f);
  float t = __builtin_amdgcn_exp2f(x * 2.885390081777927f);  // 2*log2(e)
  return (t - 1.0f) * __builtin_amdgcn_rcpf(t + 1.0f);
}

// ---- K0: sentinel-fill hchain slots 1..256, hidden -> slot 0, zero flags
__global__ void k_init(const float* __restrict__ hidden, uint16_t* __restrict__ hch,
                       uint32_t* __restrict__ flg){
  long idx = (long)blockIdx.x * 256 + threadIdx.x;   // grid 2048*256 = 524,288
  ((u32x4*)(hch + (long)NB * NH))[idx] = (u32x4){~0u, ~0u, ~0u, ~0u};
  if (idx < NB * NH) hch[idx] = f2bf(hidden[idx]);
  if (idx < 512) flg[idx] = 0u;                      // allvis[260] + fin[64]
}

// ---- K1: Who_w f32 -> bf16 (row-major [32000][1024])
__global__ void k_cvt(const float* __restrict__ src, uint32_t* __restrict__ dst){
  long idx = (long)blockIdx.x * 256 + threadIdx.x;  // 4,096,000 threads, 8 f32 each
  const float4* p = (const float4*)src;
  float4 a = p[idx*2], b = p[idx*2+1];
  u32x4 d;
  d[0] = (uint32_t)f2bf(a.x) | ((uint32_t)f2bf(a.y) << 16);
  d[1] = (uint32_t)f2bf(a.z) | ((uint32_t)f2bf(a.w) << 16);
  d[2] = (uint32_t)f2bf(b.x) | ((uint32_t)f2bf(b.y) << 16);
  d[3] = (uint32_t)f2bf(b.z) | ((uint32_t)f2bf(b.w) << 16);
  ((u32x4*)dst)[idx] = d;
}

// ---- K2: xp[m][n] = sum_k emb(ids[m])[k] * Wxh[n][k] + b[n]   (m=(b,s), bf16 MFMA)
__global__ __launch_bounds__(256) void k_xproj(
    const int* __restrict__ ids, const float* __restrict__ tab,
    const float* __restrict__ wxh, const float* __restrict__ bxh,
    float* __restrict__ xp){
  int bid = blockIdx.x;                 // 64 M-tiles x 16 N-tiles
  int tm = bid & 63, tn = bid >> 6;
  int Mb = tm * 64, Nb = tn * 64;
  int tid = threadIdx.x;
  int w = tid >> 6, l = tid & 63;
  int lr = l & 15, lk = l >> 4;

  int m = Mb + w*16 + lr;
  int id = ids[m];
  const float* arow = tab + (long)id * NE;
  bool pad = (id == PAD_IDX);

  f32x4 acc[4];
  #pragma unroll
  for (int j = 0; j < 4; ++j) acc[j] = (f32x4){0.f,0.f,0.f,0.f};

  for (int k0 = 0; k0 < NE; k0 += 32){
    int k = k0 + lk*8;
    bf16x8 af = (bf16x8){0,0,0,0,0,0,0,0};
    if (!pad){
      float4 a = *(const float4*)(arow + k);
      float4 b = *(const float4*)(arow + k + 4);
      af = pack8(a, b);
    }
    #pragma unroll
    for (int j = 0; j < 4; ++j){
      const float* brow = wxh + (long)(Nb + j*16 + lr) * NE + k;
      float4 x = *(const float4*)brow;
      float4 y = *(const float4*)(brow + 4);
      bf16x8 bf_ = pack8(x, y);
      acc[j] = __builtin_amdgcn_mfma_f32_16x16x32_bf16(af, bf_, acc[j], 0, 0, 0);
    }
  }
  #pragma unroll
  for (int j = 0; j < 4; ++j){
    int n = Nb + j*16 + lr;
    float bias = bxh[n];
    #pragma unroll
    for (int r = 0; r < 4; ++r){
      int row = Mb + w*16 + lk*4 + r;
      xp[(long)row * NH + n] = acc[j][r] + bias;
    }
  }
}

// ---- K3 fused (R12 structure; RNN now 4-wave split-K).
// RNN (bids 0..63): 4 waves, wave wv owns K-quarter [wv*256,+256) (Whh slice
//   in 32 VGPR); per step one sentinel data-poll of 8 coherent 16B frags per
//   lane (shorter drain -> finer detect sampling than 2-wave's 16); partial
//   combine via LDS ping-pong (waves 1..3 -> wave 0), tanh, coalesced
//   write-through store of slot t+1. Block 0 publishes allvis[t] after the
//   combine barrier: all 4 waves' poll passes prove slot t fully at L3.
//   fin[role] certifies slot 256.
// GEMM (bids 64..8063): reg-staged 128x128, s-major M (tile tm spans 8 steps),
//   gated on allvis[tm*8+8] (4 B, one shared line) or fin[0..63] for tm=31;
//   out written with nt to keep whobf L3-resident.
__global__ __launch_bounds__(256, 2) void k_fused(
    const float* __restrict__ whh, const float* __restrict__ xp,
    uint16_t* __restrict__ hch, const uint16_t* __restrict__ whobf,
    const float* __restrict__ whob, uint32_t* __restrict__ allvis,
    uint32_t* __restrict__ fin, float* __restrict__ out,
    float* __restrict__ hfin){
  __shared__ __align__(16) char smem[17*1024];
  const int bid = blockIdx.x;
  const int tid = threadIdx.x;

  if (bid < 64){
    // ================= RNN path (4 waves, split-K) =================
    f32x4*    accbuf = (f32x4*)smem;                 // [2][3][64] f32x4, 6 KB
    uint16_t* hs2    = (uint16_t*)(smem + 6144);     // [2][256] bf16, 1 KB
    const int wv = tid >> 6;        // 0..3 (K-quarter)
    const int l  = tid & 63;
    const int j0 = bid * 16;
    const int lr = l & 15, lk = l >> 4;
    __builtin_amdgcn_s_setprio(2);

    // Whh fragments for this wave's K-quarter -> registers (32 VGPR)
    bf16x8 bfrag[8];
    #pragma unroll
    for (int kk = 0; kk < 8; ++kk){
      const float* s0 = whh + (long)(j0 + lr) * NH + (wv*8 + kk)*32 + lk*8;
      float4 a = *(const float4*)s0;
      float4 b = *(const float4*)(s0 + 4);
      bfrag[kk] = pack8(a, b);
    }

    float xpreg[4];
    if (wv == 0){
      #pragma unroll
      for (int r = 0; r < 4; ++r)
        xpreg[r] = xp[((long)(lk*4 + r) * NS + 0) * NH + j0 + lr];
    }

    const char* hbase = (const char*)hch;
    for (int t = 0; t < NS; ++t){
      // poll this wave's K-quarter of slot t: h[batch=lr][k=(wv*8+kk)*32+lk*8]
      const char* hsrc = hbase + (long)t * NB * NH * 2 + lr * 2048 + wv * 512 + lk * 16;
      u32x4 hfrag[8];
      while (true){
        #pragma unroll
        for (int kk = 0; kk < 8; ++kk)
          hfrag[kk] = load_coh16(hsrc + kk * 64);
        asm volatile("s_waitcnt vmcnt(0)" ::: "memory");
        __builtin_amdgcn_sched_barrier(0);   // pin check AFTER waitcnt (rule #18)
        u32x4 m4 = hfrag[0];
        #pragma unroll
        for (int kk = 1; kk < 8; ++kk) m4 = umax4(m4, hfrag[kk]);
        uint32_t m01 = m4[0] > m4[1] ? m4[0] : m4[1];
        uint32_t m23 = m4[2] > m4[3] ? m4[2] : m4[3];
        uint32_t m = m01 > m23 ? m01 : m23;
        if (__all(m != 0xFFFFFFFFu)) break;
      }
      __builtin_amdgcn_sched_barrier(0);

      f32x4 a0 = (f32x4){0.f,0.f,0.f,0.f}, a1 = a0;
      #pragma unroll
      for (int kk = 0; kk < 8; kk += 2){
        a0 = __builtin_amdgcn_mfma_f32_16x16x32_bf16(*(const bf16x8*)&hfrag[kk  ], bfrag[kk  ], a0, 0, 0, 0);
        a1 = __builtin_amdgcn_mfma_f32_16x16x32_bf16(*(const bf16x8*)&hfrag[kk+1], bfrag[kk+1], a1, 0, 0, 0);
      }
      f32x4 acc = a0 + a1;

      if (wv != 0)
        accbuf[((t & 1)*3 + (wv-1))*64 + l] = acc;    // partials -> wave0
      __syncthreads();   // all 4 waves' polls passed; slot t fully read

      if (wv == 0){
        // block 0's poll pass proves ALL of slot t is at L3 -> publish
        if (bid == 0 && l == 0) store_coh4(allvis + t, 1u);
        f32x4 o0 = accbuf[((t & 1)*3 + 0)*64 + l];
        f32x4 o1 = accbuf[((t & 1)*3 + 1)*64 + l];
        f32x4 o2 = accbuf[((t & 1)*3 + 2)*64 + l];
        f32x4 osum = (acc + o0) + (o1 + o2);
        uint16_t* hb = hs2 + (t & 1)*256;
        #pragma unroll
        for (int r = 0; r < 4; ++r){
          int b = lk*4 + r;                           // C/D: row=(l>>4)*4+r, col=l&15
          float hv = tanh_fast(xpreg[r] + osum[r]);
          hb[b*16 + lr] = f2bf(hv);
          if (t == NS-1) hfin[b*NH + j0 + lr] = hv;
        }
        asm volatile("s_waitcnt lgkmcnt(0)" ::: "memory");
        __builtin_amdgcn_sched_barrier(0);
        // coalesced write-through store of slot t+1 slice (fire-and-forget)
        int rb = l >> 2, cc = l & 3;
        uint32_t w0 = *(const uint32_t*)&hb[rb*16 + cc*4];
        uint32_t w1 = *(const uint32_t*)&hb[rb*16 + cc*4 + 2];
        char* dst = (char*)hch + (long)(t+1) * NB * NH * 2 + rb * 2048 + j0*2 + cc*8;
        store_coh8(dst, ((uint64_t)w1 << 32) | (uint64_t)w0);
        if (t + 1 < NS){
          #pragma unroll
          for (int r = 0; r < 4; ++r)
            xpreg[r] = xp[((long)(lk*4 + r) * NS + (t+1)) * NH + j0 + lr];
        }
      }
    }
    if (wv == 0){
      asm volatile("s_waitcnt vmcnt(0)" ::: "memory");   // slot-256 stores acked
      if (l == 0) store_coh4(fin + bid, 1u);
    }
    return;
  }

  // ================= logits path (reg-staged, s-major tiles) =================
  uint16_t* As = (uint16_t*)smem;          // 8 KB
  uint16_t* Bs = (uint16_t*)(smem + 8192); // 8 KB
  int tile = bid - 64;                     // 0..7999
  int tm = tile / 250;                     // s-group (8 steps per tile)
  int tn = tile % 250;
  int Mb = tm * 128, Nb = tn * 128;
  int hs = tm * 8 + 8;                     // highest needed slot

  if (hs < 256){                           // gate: ONE u32 (shared line)
    while (true){
      uint32_t f = load_coh4(allvis + hs);
      asm volatile("s_waitcnt vmcnt(0)" ::: "memory");
      __builtin_amdgcn_sched_barrier(0);
      if (__syncthreads_count(f == 0u) == 0) break;
      __builtin_amdgcn_s_sleep(16);
    }
  } else {                                 // last s-group: 64 per-block finals
    const uint32_t* gp = fin + (tid & 63);
    while (true){
      uint32_t f = load_coh4(gp);
      asm volatile("s_waitcnt vmcnt(0)" ::: "memory");
      __builtin_amdgcn_sched_barrier(0);
      if (__syncthreads_count(f == 0u) == 0) break;
      __builtin_amdgcn_s_sleep(16);
    }
  }

  int wv = tid >> 6, l = tid & 63;
  int wm = wv >> 1, wn = wv & 1;
  int lr = l & 15, lk = l >> 4;

  int r0 = tid >> 2, c0 = tid & 3;
  int r1 = r0 + 64;
  // s-major: A row m <-> hchain row m+16 (contiguous)
  const uint16_t* pa0 = hch + (long)(Mb + r0 + 16) * NH + c0*8;
  const uint16_t* pa1 = hch + (long)(Mb + r1 + 16) * NH + c0*8;
  const uint16_t* pb0 = whobf + (long)(Nb + r0) * NH + c0*8;
  const uint16_t* pb1 = whobf + (long)(Nb + r1) * NH + c0*8;
  int da0 = r0*4 + (c0 ^ (r0 & 3));
  int da1 = r1*4 + (c0 ^ (r1 & 3));

  u32x4 ra0 = *(const u32x4*)pa0;
  u32x4 ra1 = *(const u32x4*)pa1;
  u32x4 rb0 = *(const u32x4*)pb0;
  u32x4 rb1 = *(const u32x4*)pb1;

  f32x4 acc[4][4];
  #pragma unroll
  for (int i = 0; i < 4; ++i)
    #pragma unroll
    for (int jj = 0; jj < 4; ++jj) acc[i][jj] = (f32x4){0.f,0.f,0.f,0.f};

  for (int kt = 0; kt < 32; ++kt){
    ((u32x4*)As)[da0] = ra0;
    ((u32x4*)As)[da1] = ra1;
    ((u32x4*)Bs)[da0] = rb0;
    ((u32x4*)Bs)[da1] = rb1;
    __syncthreads();
    if (kt != 31){
      int off = (kt + 1) * 32;
      ra0 = *(const u32x4*)(pa0 + off);
      ra1 = *(const u32x4*)(pa1 + off);
      rb0 = *(const u32x4*)(pb0 + off);
      rb1 = *(const u32x4*)(pb1 + off);
    }
    bf16x8 af[4], bg_[4];
    #pragma unroll
    for (int i = 0; i < 4; ++i){
      int ra = wm*64 + i*16 + lr;
      int rb = wn*64 + i*16 + lr;
      af[i]  = *(const bf16x8*)&((const u32x4*)As)[ra*4 + (lk ^ (ra & 3))];
      bg_[i] = *(const bf16x8*)&((const u32x4*)Bs)[rb*4 + (lk ^ (rb & 3))];
    }
    #pragma unroll
    for (int i = 0; i < 4; ++i)
      #pragma unroll
      for (int jj = 0; jj < 4; ++jj)
        acc[i][jj] = __builtin_amdgcn_mfma_f32_16x16x32_bf16(af[i], bg_[jj], acc[i][jj], 0, 0, 0);
    __syncthreads();
  }

  #pragma unroll
  for (int jj = 0; jj < 4; ++jj){
    int col = Nb + wn*64 + jj*16 + lr;
    float bias = whob[col];
    #pragma unroll
    for (int i = 0; i < 4; ++i){
      #pragma unroll
      for (int rr = 0; rr < 4; ++rr){
        int m = Mb + wm*64 + i*16 + lk*4 + rr;      // m = s*16 + b
        long orow = (long)((m & 15) * 256 + (m >> 4));
        store_nt4(&out[orow * NV + col], acc[i][jj][rr] + bias);
      }
    }
  }
}

extern "C" void kernel_launch(void* const* d_in, const int* in_sizes, int n_in,
                              void* d_out, int out_size, void* d_ws, size_t ws_size,
                              hipStream_t stream){
  (void)in_sizes; (void)n_in; (void)out_size;
  if (ws_size < (size_t)WS_NEED) return;   // insufficient scratch -> fail loudly

  const int*   ids    = (const int*)  d_in[0];
  const float* hidden = (const float*)d_in[1];
  const float* table  = (const float*)d_in[2];
  const float* wxh    = (const float*)d_in[3];
  const float* bxh    = (const float*)d_in[4];
  const float* whh    = (const float*)d_in[5];
  const float* who    = (const float*)d_in[6];
  const float* whob   = (const float*)d_in[7];

  char* ws = (char*)d_ws;
  float*    xp     = (float*)   (ws + WS_XP);
  uint16_t* hchain = (uint16_t*)(ws + WS_HCH);
  uint16_t* whobf  = (uint16_t*)(ws + WS_WHO);
  uint32_t* allvis = (uint32_t*)(ws + WS_FLG);     // [260]
  uint32_t* fin    = allvis + 260;                 // [64]
  float* out    = (float*)d_out;
  float* hfinal = out + (long)NB * NS * NV;   // 131,072,000

  k_init <<<2048,  256, 0, stream>>>(hidden, hchain, allvis);
  k_cvt  <<<16000, 256, 0, stream>>>(who, (uint32_t*)whobf);
  k_xproj<<<1024,  256, 0, stream>>>(ids, table, wxh, bxh, xp);
  k_fused<<<8064,  256, 0, stream>>>(whh, xp, hchain, whobf, whob,
                                     allvis, fin, out, hfinal);
}

// Round 16
// 1001.501 us; speedup vs baseline: 1.2099x; 1.1248x over previous
//
#include <hip/hip_runtime.h>
#include <stdint.h>

#define NB 16
#define NS 256
#define NV 32000
#define NE 512
#define NH 1024
#define PAD_IDX 3

// workspace byte offsets
#define WS_XP    0L                 // f32 [4096][1024]   16,777,216 B
#define WS_HCH   16777216L          // bf16 [257][16][1024] 8,421,376 B
#define WS_WHO   25198592L          // bf16 [32000][1024] 65,536,000 B
#define WS_FLG   90734592L          // u32 allvis[260] + fin[64]
#define WS_NEED  90800384L

typedef __attribute__((ext_vector_type(8))) short bf16x8;
typedef __attribute__((ext_vector_type(4))) float f32x4;
typedef __attribute__((ext_vector_type(4))) uint32_t u32x4;

__device__ __forceinline__ uint16_t f2bf(float f){
  union { float f; uint32_t u; } v; v.f = f;
  return (uint16_t)((v.u + 0x7fffu + ((v.u >> 16) & 1u)) >> 16);  // RNE
}

__device__ __forceinline__ bf16x8 pack8(float4 a, float4 b){
  bf16x8 r;
  r[0]=(short)f2bf(a.x); r[1]=(short)f2bf(a.y); r[2]=(short)f2bf(a.z); r[3]=(short)f2bf(a.w);
  r[4]=(short)f2bf(b.x); r[5]=(short)f2bf(b.y); r[6]=(short)f2bf(b.z); r[7]=(short)f2bf(b.w);
  return r;
}

// device-coherent (L3) ops: bypass L1+L2
__device__ __forceinline__ u32x4 load_coh16(const void* p){
  u32x4 r;
  asm volatile("global_load_dwordx4 %0, %1, off sc0 sc1" : "=v"(r) : "v"(p) : "memory");
  return r;
}
__device__ __forceinline__ uint32_t load_coh4(const void* p){
  uint32_t r;
  asm volatile("global_load_dword %0, %1, off sc0 sc1" : "=v"(r) : "v"(p) : "memory");
  return r;
}
__device__ __forceinline__ void store_coh8(void* p, uint64_t v){
  asm volatile("global_store_dwordx2 %0, %1, off sc0 sc1" :: "v"(p), "v"(v) : "memory");
}
__device__ __forceinline__ void store_coh4(void* p, uint32_t v){
  asm volatile("global_store_dword %0, %1, off sc0 sc1" :: "v"(p), "v"(v) : "memory");
}
// non-temporal store: don't pollute L3 with the 524 MB out stream
__device__ __forceinline__ void store_nt4(void* p, float v){
  asm volatile("global_store_dword %0, %1, off nt" :: "v"(p), "v"(v) : "memory");
}

__device__ __forceinline__ u32x4 umax4(u32x4 a, u32x4 b){
  u32x4 r;
  r[0] = a[0] > b[0] ? a[0] : b[0];
  r[1] = a[1] > b[1] ? a[1] : b[1];
  r[2] = a[2] > b[2] ? a[2] : b[2];
  r[3] = a[3] > b[3] ? a[3] : b[3];
  return r;
}

// clamped fast tanh; abs err ~1e-5, never NaN/inf (|out|<=1 -> bf16 never 0xFFFF)
__device__ __forceinline__ float tanh_fast(float x){
  x = fminf(fmaxf(x, -10.f), 10.f);
  float t = __builtin_amdgcn_exp2f(x * 2.885390081777927f);  // 2*log2(e)
  return (t - 1.0f) * __builtin_amdgcn_rcpf(t + 1.0f);
}

// ---- K0: sentinel-fill hchain slots 1..256, hidden -> slot 0, zero flags
__global__ void k_init(const float* __restrict__ hidden, uint16_t* __restrict__ hch,
                       uint32_t* __restrict__ flg){
  long idx = (long)blockIdx.x * 256 + threadIdx.x;   // grid 2048*256 = 524,288
  ((u32x4*)(hch + (long)NB * NH))[idx] = (u32x4){~0u, ~0u, ~0u, ~0u};
  if (idx < NB * NH) hch[idx] = f2bf(hidden[idx]);
  if (idx < 512) flg[idx] = 0u;                      // allvis[260] + fin[64]
}

// ---- K1: Who_w f32 -> bf16 (row-major [32000][1024])
__global__ void k_cvt(const float* __restrict__ src, uint32_t* __restrict__ dst){
  long idx = (long)blockIdx.x * 256 + threadIdx.x;  // 4,096,000 threads, 8 f32 each
  const float4* p = (const float4*)src;
  float4 a = p[idx*2], b = p[idx*2+1];
  u32x4 d;
  d[0] = (uint32_t)f2bf(a.x) | ((uint32_t)f2bf(a.y) << 16);
  d[1] = (uint32_t)f2bf(a.z) | ((uint32_t)f2bf(a.w) << 16);
  d[2] = (uint32_t)f2bf(b.x) | ((uint32_t)f2bf(b.y) << 16);
  d[3] = (uint32_t)f2bf(b.z) | ((uint32_t)f2bf(b.w) << 16);
  ((u32x4*)dst)[idx] = d;
}

// ---- K2: xp[m][n] = sum_k emb(ids[m])[k] * Wxh[n][k] + b[n]   (m=(b,s), bf16 MFMA)
__global__ __launch_bounds__(256) void k_xproj(
    const int* __restrict__ ids, const float* __restrict__ tab,
    const float* __restrict__ wxh, const float* __restrict__ bxh,
    float* __restrict__ xp){
  int bid = blockIdx.x;                 // 64 M-tiles x 16 N-tiles
  int tm = bid & 63, tn = bid >> 6;
  int Mb = tm * 64, Nb = tn * 64;
  int tid = threadIdx.x;
  int w = tid >> 6, l = tid & 63;
  int lr = l & 15, lk = l >> 4;

  int m = Mb + w*16 + lr;
  int id = ids[m];
  const float* arow = tab + (long)id * NE;
  bool pad = (id == PAD_IDX);

  f32x4 acc[4];
  #pragma unroll
  for (int j = 0; j < 4; ++j) acc[j] = (f32x4){0.f,0.f,0.f,0.f};

  for (int k0 = 0; k0 < NE; k0 += 32){
    int k = k0 + lk*8;
    bf16x8 af = (bf16x8){0,0,0,0,0,0,0,0};
    if (!pad){
      float4 a = *(const float4*)(arow + k);
      float4 b = *(const float4*)(arow + k + 4);
      af = pack8(a, b);
    }
    #pragma unroll
    for (int j = 0; j < 4; ++j){
      const float* brow = wxh + (long)(Nb + j*16 + lr) * NE + k;
      float4 x = *(const float4*)brow;
      float4 y = *(const float4*)(brow + 4);
      bf16x8 bf_ = pack8(x, y);
      acc[j] = __builtin_amdgcn_mfma_f32_16x16x32_bf16(af, bf_, acc[j], 0, 0, 0);
    }
  }
  #pragma unroll
  for (int j = 0; j < 4; ++j){
    int n = Nb + j*16 + lr;
    float bias = bxh[n];
    #pragma unroll
    for (int r = 0; r < 4; ++r){
      int row = Mb + w*16 + lk*4 + r;
      xp[(long)row * NH + n] = acc[j][r] + bias;
    }
  }
}

// ---- K3 fused (16-block RNN, full-K waves; GEMM = R14 engine).
// RNN (bids 0..15): block owns 64 cols; 4 waves x 16 cols; each wave holds its
//   full-K Whh slice in 128 VGPR. Per step: each wave sentinel-polls one
//   K-QUARTER of the FULL slot, writes it to XOR-swizzled LDS, then
//   __syncthreads() (R15 ERRATUM: a relaxed LDS-counter spin does NOT order
//   the other waves' LDS writes vs this wave's MFMA ds_reads — compiler may
//   hoist the reads; the real barrier provides the LDS fence). Then MFMA full
//   K (no partial-sum exchange), tanh, hs2 transpose, second __syncthreads,
//   coalesced 8B write-through of the block's 64-col slice of slot t+1.
//   Block 0 read the ENTIRE slot coherently -> allvis[t] single 4B gate.
//   fin[bid] certifies slot 256. LDS single-buffer safe by 2-barrier
//   induction (hlds writes for t+1 postdate barrier 2 of step t, which
//   postdates all hlds reads for t).
// GEMM (bids 16..8015): reg-staged 128x128, s-major M (tile tm spans 8 steps),
//   gated on allvis[tm*8+8] or fin[0..15] for tm=31; nt out stores.
__global__ __launch_bounds__(256, 2) void k_fused(
    const float* __restrict__ whh, const float* __restrict__ xp,
    uint16_t* __restrict__ hch, const uint16_t* __restrict__ whobf,
    const float* __restrict__ whob, uint32_t* __restrict__ allvis,
    uint32_t* __restrict__ fin, float* __restrict__ out,
    float* __restrict__ hfin){
  __shared__ __align__(16) char smem[35*1024];
  const int bid = blockIdx.x;
  const int tid = threadIdx.x;

  if (bid < 16){
    // ================= RNN path (4 waves, full-K per wave) =================
    uint16_t* hlds = (uint16_t*)smem;             // [16][128] 16B-chunks swizzled, 32 KB
    uint16_t* hs2  = (uint16_t*)(smem + 32768);   // [16][64] bf16, 2 KB
    const int wv = tid >> 6, l = tid & 63;
    const int lr = l & 15, lk = l >> 4;
    const int base = bid*64 + wv*16;              // first col owned by this wave
    __builtin_amdgcn_s_setprio(2);

    // full-K weight slice: wf[kk] = Whh[base+lr][kk*32 + lk*8 .. +7] (128 VGPR)
    bf16x8 wf[32];
    #pragma unroll
    for (int kk = 0; kk < 32; ++kk){
      const float* s0 = whh + (long)(base + lr) * NH + kk*32 + lk*8;
      wf[kk] = pack8(*(const float4*)s0, *(const float4*)(s0 + 4));
    }

    float xpreg[4];
    #pragma unroll
    for (int r = 0; r < 4; ++r)
      xpreg[r] = xp[((long)(lk*4 + r) * NS + 0) * NH + base + lr];

    for (int t = 0; t < NS; ++t){
      // ---- poll own K-quarter of the full slot t:
      // lane l covers batch l>>2, k-bytes [wv*512 + (l&3)*128, +128)
      {
        const char* ps = (const char*)hch + ((long)t * NB + (l >> 2)) * 2048
                       + wv*512 + (l & 3)*128;
        u32x4 hf[8];
        while (true){
          #pragma unroll
          for (int j = 0; j < 8; ++j) hf[j] = load_coh16(ps + j*16);
          asm volatile("s_waitcnt vmcnt(0)" ::: "memory");
          __builtin_amdgcn_sched_barrier(0);   // pin check AFTER waitcnt (rule #18)
          u32x4 m4 = hf[0];
          #pragma unroll
          for (int j = 1; j < 8; ++j) m4 = umax4(m4, hf[j]);
          uint32_t m01 = m4[0] > m4[1] ? m4[0] : m4[1];
          uint32_t m23 = m4[2] > m4[3] ? m4[2] : m4[3];
          uint32_t m = m01 > m23 ? m01 : m23;
          if (__all(m != 0xFFFFFFFFu)) break;
        }
        __builtin_amdgcn_sched_barrier(0);
        // publish quarter to LDS, chunk-swizzled: chunk (batch, cib) ->
        // hlds[batch*128 + (cib ^ (batch&7))]
        int batch = l >> 2;
        #pragma unroll
        for (int j = 0; j < 8; ++j){
          int cib = wv*32 + (l & 3)*8 + j;
          ((u32x4*)hlds)[batch*128 + (cib ^ (batch & 7))] = hf[j];
        }
      }
      __syncthreads();   // REAL barrier: all quarters in LDS, fenced (R15 fix)
      // block 0 read the ENTIRE slot t coherently -> certify (single 4B flag)
      if (bid == 0 && tid == 0) store_coh4(allvis + t, 1u);

      // ---- full-K MFMA: af = h[batch lr][k chunk kk*4+lk] (swizzled read,
      // 2 lanes/bank = free); acc rows = batches, col = lr
      f32x4 a0 = (f32x4){0.f,0.f,0.f,0.f}, a1 = a0;
      #pragma unroll
      for (int kk = 0; kk < 32; kk += 2){
        bf16x8 af0 = *(const bf16x8*)&((const u32x4*)hlds)[lr*128 + (( kk   *4 + lk) ^ (lr & 7))];
        bf16x8 af1 = *(const bf16x8*)&((const u32x4*)hlds)[lr*128 + (((kk+1)*4 + lk) ^ (lr & 7))];
        a0 = __builtin_amdgcn_mfma_f32_16x16x32_bf16(af0, wf[kk  ], a0, 0, 0, 0);
        a1 = __builtin_amdgcn_mfma_f32_16x16x32_bf16(af1, wf[kk+1], a1, 0, 0, 0);
      }
      f32x4 acc = a0 + a1;

      // tanh + transpose via hs2 (C/D: row=(l>>4)*4+r = batch, col=l&15)
      #pragma unroll
      for (int r = 0; r < 4; ++r){
        float hv = tanh_fast(xpreg[r] + acc[r]);
        hs2[(lk*4 + r)*64 + wv*16 + lr] = f2bf(hv);
        if (t == NS-1) hfin[(long)(lk*4 + r) * NH + base + lr] = hv;
      }
      __syncthreads();   // hs2 complete; also closes hlds reuse for t+1

      // coalesced write-through store of the block's 64-col slice of slot t+1
      {
        int row = tid >> 4, ch = tid & 15;     // 16 rows x 16 chunks of 8B
        uint64_t v = *(const uint64_t*)&hs2[row*64 + ch*4];
        char* dst = (char*)hch + ((long)(t+1) * NB + row) * 2048 + (bid*64 + ch*4)*2;
        store_coh8(dst, v);
      }
      if (t + 1 < NS){
        #pragma unroll
        for (int r = 0; r < 4; ++r)
          xpreg[r] = xp[((long)(lk*4 + r) * NS + (t+1)) * NH + base + lr];
      }
    }
    asm volatile("s_waitcnt vmcnt(0)" ::: "memory");   // slot-256 stores acked
    __syncthreads();
    if (tid == 0) store_coh4(fin + bid, 1u);
    return;
  }

  // ================= logits path (R14 engine: reg-staged, s-major) ==========
  uint16_t* As = (uint16_t*)smem;          // 8 KB
  uint16_t* Bs = (uint16_t*)(smem + 8192); // 8 KB
  int tile = bid - 16;                     // 0..7999
  int tm = tile / 250;                     // s-group (8 steps per tile)
  int tn = tile % 250;
  int Mb = tm * 128, Nb = tn * 128;
  int hs = tm * 8 + 8;                     // highest needed slot

  if (hs < 256){                           // gate: ONE u32 (shared line)
    while (true){
      uint32_t f = load_coh4(allvis + hs);
      asm volatile("s_waitcnt vmcnt(0)" ::: "memory");
      __builtin_amdgcn_sched_barrier(0);
      if (__syncthreads_count(f == 0u) == 0) break;
      __builtin_amdgcn_s_sleep(16);
    }
  } else {                                 // last s-group: 16 per-block finals
    const uint32_t* gp = fin + (tid & 15);
    while (true){
      uint32_t f = load_coh4(gp);
      asm volatile("s_waitcnt vmcnt(0)" ::: "memory");
      __builtin_amdgcn_sched_barrier(0);
      if (__syncthreads_count(f == 0u) == 0) break;
      __builtin_amdgcn_s_sleep(16);
    }
  }

  int wv = tid >> 6, l = tid & 63;
  int wm = wv >> 1, wn = wv & 1;
  int lr = l & 15, lk = l >> 4;

  int r0 = tid >> 2, c0 = tid & 3;
  int r1 = r0 + 64;
  // s-major: A row m <-> hchain row m+16 (contiguous)
  const uint16_t* pa0 = hch + (long)(Mb + r0 + 16) * NH + c0*8;
  const uint16_t* pa1 = hch + (long)(Mb + r1 + 16) * NH + c0*8;
  const uint16_t* pb0 = whobf + (long)(Nb + r0) * NH + c0*8;
  const uint16_t* pb1 = whobf + (long)(Nb + r1) * NH + c0*8;
  int da0 = r0*4 + (c0 ^ (r0 & 3));
  int da1 = r1*4 + (c0 ^ (r1 & 3));

  u32x4 ra0 = *(const u32x4*)pa0;
  u32x4 ra1 = *(const u32x4*)pa1;
  u32x4 rb0 = *(const u32x4*)pb0;
  u32x4 rb1 = *(const u32x4*)pb1;

  f32x4 acc[4][4];
  #pragma unroll
  for (int i = 0; i < 4; ++i)
    #pragma unroll
    for (int jj = 0; jj < 4; ++jj) acc[i][jj] = (f32x4){0.f,0.f,0.f,0.f};

  for (int kt = 0; kt < 32; ++kt){
    ((u32x4*)As)[da0] = ra0;
    ((u32x4*)As)[da1] = ra1;
    ((u32x4*)Bs)[da0] = rb0;
    ((u32x4*)Bs)[da1] = rb1;
    __syncthreads();
    if (kt != 31){
      int off = (kt + 1) * 32;
      ra0 = *(const u32x4*)(pa0 + off);
      ra1 = *(const u32x4*)(pa1 + off);
      rb0 = *(const u32x4*)(pb0 + off);
      rb1 = *(const u32x4*)(pb1 + off);
    }
    bf16x8 af[4], bg_[4];
    #pragma unroll
    for (int i = 0; i < 4; ++i){
      int ra = wm*64 + i*16 + lr;
      int rb = wn*64 + i*16 + lr;
      af[i]  = *(const bf16x8*)&((const u32x4*)As)[ra*4 + (lk ^ (ra & 3))];
      bg_[i] = *(const bf16x8*)&((const u32x4*)Bs)[rb*4 + (lk ^ (rb & 3))];
    }
    #pragma unroll
    for (int i = 0; i < 4; ++i)
      #pragma unroll
      for (int jj = 0; jj < 4; ++jj)
        acc[i][jj] = __builtin_amdgcn_mfma_f32_16x16x32_bf16(af[i], bg_[jj], acc[i][jj], 0, 0, 0);
    __syncthreads();
  }

  #pragma unroll
  for (int jj = 0; jj < 4; ++jj){
    int col = Nb + wn*64 + jj*16 + lr;
    float bias = whob[col];
    #pragma unroll
    for (int i = 0; i < 4; ++i){
      #pragma unroll
      for (int rr = 0; rr < 4; ++rr){
        int m = Mb + wm*64 + i*16 + lk*4 + rr;      // m = s*16 + b
        long orow = (long)((m & 15) * 256 + (m >> 4));
        store_nt4(&out[orow * NV + col], acc[i][jj][rr] + bias);
      }
    }
  }
}

extern "C" void kernel_launch(void* const* d_in, const int* in_sizes, int n_in,
                              void* d_out, int out_size, void* d_ws, size_t ws_size,
                              hipStream_t stream){
  (void)in_sizes; (void)n_in; (void)out_size;
  if (ws_size < (size_t)WS_NEED) return;   // insufficient scratch -> fail loudly

  const int*   ids    = (const int*)  d_in[0];
  const float* hidden = (const float*)d_in[1];
  const float* table  = (const float*)d_in[2];
  const float* wxh    = (const float*)d_in[3];
  const float* bxh    = (const float*)d_in[4];
  const float* whh    = (const float*)d_in[5];
  const float* who    = (const float*)d_in[6];
  const float* whob   = (const float*)d_in[7];

  char* ws = (char*)d_ws;
  float*    xp     = (float*)   (ws + WS_XP);
  uint16_t* hchain = (uint16_t*)(ws + WS_HCH);
  uint16_t* whobf  = (uint16_t*)(ws + WS_WHO);
  uint32_t* allvis = (uint32_t*)(ws + WS_FLG);     // [260]
  uint32_t* fin    = allvis + 260;                 // [64]
  float* out    = (float*)d_out;
  float* hfinal = out + (long)NB * NS * NV;   // 131,072,000

  k_init <<<2048,  256, 0, stream>>>(hidden, hchain, allvis);
  k_cvt  <<<16000, 256, 0, stream>>>(who, (uint32_t*)whobf);
  k_xproj<<<1024,  256, 0, stream>>>(ids, table, wxh, bxh, xp);
  k_fused<<<8016,  256, 0, stream>>>(whh, xp, hchain, whobf, whob,
                                     allvis, fin, out, hfinal);
}

// Round 17
// 947.634 us; speedup vs baseline: 1.2787x; 1.0568x over previous
//
#include <hip/hip_runtime.h>
#include <stdint.h>

#define NB 16
#define NS 256
#define NV 32000
#define NE 512
#define NH 1024
#define PAD_IDX 3

// workspace byte offsets
#define WS_XP    0L                 // f32 [4096][1024]   16,777,216 B
#define WS_HCH   16777216L          // bf16 [257][16][1024] 8,421,376 B
#define WS_WHO   25198592L          // bf16 [32000][1024] 65,536,000 B
#define WS_FLG   90734592L          // u32 allvis[260] + fin[8]
#define WS_NEED  90800384L

typedef __attribute__((ext_vector_type(8))) short bf16x8;
typedef __attribute__((ext_vector_type(4))) float f32x4;
typedef __attribute__((ext_vector_type(4))) uint32_t u32x4;

__device__ __forceinline__ uint16_t f2bf(float f){
  union { float f; uint32_t u; } v; v.f = f;
  return (uint16_t)((v.u + 0x7fffu + ((v.u >> 16) & 1u)) >> 16);  // RNE
}

__device__ __forceinline__ bf16x8 pack8(float4 a, float4 b){
  bf16x8 r;
  r[0]=(short)f2bf(a.x); r[1]=(short)f2bf(a.y); r[2]=(short)f2bf(a.z); r[3]=(short)f2bf(a.w);
  r[4]=(short)f2bf(b.x); r[5]=(short)f2bf(b.y); r[6]=(short)f2bf(b.z); r[7]=(short)f2bf(b.w);
  return r;
}

// device-coherent (L3) ops: bypass L1+L2
__device__ __forceinline__ u32x4 load_coh16(const void* p){
  u32x4 r;
  asm volatile("global_load_dwordx4 %0, %1, off sc0 sc1" : "=v"(r) : "v"(p) : "memory");
  return r;
}
__device__ __forceinline__ uint32_t load_coh4(const void* p){
  uint32_t r;
  asm volatile("global_load_dword %0, %1, off sc0 sc1" : "=v"(r) : "v"(p) : "memory");
  return r;
}
__device__ __forceinline__ void store_coh8(void* p, uint64_t v){
  asm volatile("global_store_dwordx2 %0, %1, off sc0 sc1" :: "v"(p), "v"(v) : "memory");
}
__device__ __forceinline__ void store_coh4(void* p, uint32_t v){
  asm volatile("global_store_dword %0, %1, off sc0 sc1" :: "v"(p), "v"(v) : "memory");
}
// non-temporal store: don't pollute L3 with the 524 MB out stream
__device__ __forceinline__ void store_nt4(void* p, float v){
  asm volatile("global_store_dword %0, %1, off nt" :: "v"(p), "v"(v) : "memory");
}

__device__ __forceinline__ u32x4 umax4(u32x4 a, u32x4 b){
  u32x4 r;
  r[0] = a[0] > b[0] ? a[0] : b[0];
  r[1] = a[1] > b[1] ? a[1] : b[1];
  r[2] = a[2] > b[2] ? a[2] : b[2];
  r[3] = a[3] > b[3] ? a[3] : b[3];
  return r;
}

// clamped fast tanh; abs err ~1e-5, never NaN/inf (|out|<=1 -> bf16 never 0xFFFF)
__device__ __forceinline__ float tanh_fast(float x){
  x = fminf(fmaxf(x, -10.f), 10.f);
  float t = __builtin_amdgcn_exp2f(x * 2.885390081777927f);  // 2*log2(e)
  return (t - 1.0f) * __builtin_amdgcn_rcpf(t + 1.0f);
}

// ---- K0: sentinel-fill hchain slots 1..256, hidden -> slot 0, zero flags
__global__ void k_init(const float* __restrict__ hidden, uint16_t* __restrict__ hch,
                       uint32_t* __restrict__ flg){
  long idx = (long)blockIdx.x * 256 + threadIdx.x;   // grid 2048*256 = 524,288
  ((u32x4*)(hch + (long)NB * NH))[idx] = (u32x4){~0u, ~0u, ~0u, ~0u};
  if (idx < NB * NH) hch[idx] = f2bf(hidden[idx]);
  if (idx < 512) flg[idx] = 0u;                      // allvis[260] + fin[8]
}

// ---- K1: Who_w f32 -> bf16 (row-major [32000][1024])
__global__ void k_cvt(const float* __restrict__ src, uint32_t* __restrict__ dst){
  long idx = (long)blockIdx.x * 256 + threadIdx.x;  // 4,096,000 threads, 8 f32 each
  const float4* p = (const float4*)src;
  float4 a = p[idx*2], b = p[idx*2+1];
  u32x4 d;
  d[0] = (uint32_t)f2bf(a.x) | ((uint32_t)f2bf(a.y) << 16);
  d[1] = (uint32_t)f2bf(a.z) | ((uint32_t)f2bf(a.w) << 16);
  d[2] = (uint32_t)f2bf(b.x) | ((uint32_t)f2bf(b.y) << 16);
  d[3] = (uint32_t)f2bf(b.z) | ((uint32_t)f2bf(b.w) << 16);
  ((u32x4*)dst)[idx] = d;
}

// ---- K2: xp[m][n] = sum_k emb(ids[m])[k] * Wxh[n][k] + b[n]   (m=(b,s), bf16 MFMA)
__global__ __launch_bounds__(256) void k_xproj(
    const int* __restrict__ ids, const float* __restrict__ tab,
    const float* __restrict__ wxh, const float* __restrict__ bxh,
    float* __restrict__ xp){
  int bid = blockIdx.x;                 // 64 M-tiles x 16 N-tiles
  int tm = bid & 63, tn = bid >> 6;
  int Mb = tm * 64, Nb = tn * 64;
  int tid = threadIdx.x;
  int w = tid >> 6, l = tid & 63;
  int lr = l & 15, lk = l >> 4;

  int m = Mb + w*16 + lr;
  int id = ids[m];
  const float* arow = tab + (long)id * NE;
  bool pad = (id == PAD_IDX);

  f32x4 acc[4];
  #pragma unroll
  for (int j = 0; j < 4; ++j) acc[j] = (f32x4){0.f,0.f,0.f,0.f};

  for (int k0 = 0; k0 < NE; k0 += 32){
    int k = k0 + lk*8;
    bf16x8 af = (bf16x8){0,0,0,0,0,0,0,0};
    if (!pad){
      float4 a = *(const float4*)(arow + k);
      float4 b = *(const float4*)(arow + k + 4);
      af = pack8(a, b);
    }
    #pragma unroll
    for (int j = 0; j < 4; ++j){
      const float* brow = wxh + (long)(Nb + j*16 + lr) * NE + k;
      float4 x = *(const float4*)brow;
      float4 y = *(const float4*)(brow + 4);
      bf16x8 bf_ = pack8(x, y);
      acc[j] = __builtin_amdgcn_mfma_f32_16x16x32_bf16(af, bf_, acc[j], 0, 0, 0);
    }
  }
  #pragma unroll
  for (int j = 0; j < 4; ++j){
    int n = Nb + j*16 + lr;
    float bias = bxh[n];
    #pragma unroll
    for (int r = 0; r < 4; ++r){
      int row = Mb + w*16 + lk*4 + r;
      xp[(long)row * NH + n] = acc[j][r] + bias;
    }
  }
}

// ---- K3 fused, 512-thread blocks (8-block RNN fan-in; dual-tile GEMM).
// RNN (bids 0..7): block owns 128 cols; 8 waves x 16 cols; each wave holds its
//   full-K Whh slice in 128 regs. Per step: each lane sentinel-polls 4 coherent
//   16B chunks (lane tid covers batch tid>>5, chunks (tid&31)*4+j), writes
//   them to XOR-swizzled LDS, __syncthreads (real barrier = LDS fence, R15
//   erratum), full-K MFMA (32 MFMA, no partial exchange), tanh, hs2 transpose,
//   __syncthreads, coalesced 8B write-through of the block's 128-col slice of
//   slot t+1. Block 0 read the ENTIRE slot coherently -> allvis[t] 4B gate.
//   fin[bid] certifies slot 256.
// GEMM (bids 8..4007): TWO 256-thread sub-engines per block (sub = tid>>8),
//   tiles gbid*2+sub in s-major order, each with own 16KB LDS. Gate waits on
//   the MAX hs of the two tiles (uniform across block -> barrier counts align;
//   both subs run exactly 32 kt iterations). nt out stores.
__global__ __launch_bounds__(512) void k_fused(
    const float* __restrict__ whh, const float* __restrict__ xp,
    uint16_t* __restrict__ hch, const uint16_t* __restrict__ whobf,
    const float* __restrict__ whob, uint32_t* __restrict__ allvis,
    uint32_t* __restrict__ fin, float* __restrict__ out,
    float* __restrict__ hfin){
  __shared__ __align__(16) char smem[37*1024];
  const int bid = blockIdx.x;
  const int tid = threadIdx.x;

  if (bid < 8){
    // ================= RNN path (8 waves, full-K per wave) =================
    uint16_t* hlds = (uint16_t*)smem;             // [16][128] 16B-chunks swizzled, 32 KB
    uint16_t* hs2  = (uint16_t*)(smem + 32768);   // [16][128] bf16, 4 KB
    const int wv = tid >> 6, l = tid & 63;
    const int lr = l & 15, lk = l >> 4;
    const int base = bid*128 + wv*16;             // first col owned by this wave
    __builtin_amdgcn_s_setprio(2);

    // full-K weight slice: wf[kk] = Whh[base+lr][kk*32 + lk*8 .. +7] (128 regs)
    bf16x8 wf[32];
    #pragma unroll
    for (int kk = 0; kk < 32; ++kk){
      const float* s0 = whh + (long)(base + lr) * NH + kk*32 + lk*8;
      wf[kk] = pack8(*(const float4*)s0, *(const float4*)(s0 + 4));
    }

    float xpreg[4];
    #pragma unroll
    for (int r = 0; r < 4; ++r)
      xpreg[r] = xp[((long)(lk*4 + r) * NS + 0) * NH + base + lr];

    const int pbat = tid >> 5;          // batch this lane polls
    const int pch  = tid & 31;          // 4-chunk group within the batch row

    for (int t = 0; t < NS; ++t){
      // ---- poll own 4 chunks of slot t (64 B per lane)
      {
        const char* ps = (const char*)hch + ((long)t * NB + pbat) * 2048 + pch*64;
        u32x4 hf[4];
        while (true){
          #pragma unroll
          for (int j = 0; j < 4; ++j) hf[j] = load_coh16(ps + j*16);
          asm volatile("s_waitcnt vmcnt(0)" ::: "memory");
          __builtin_amdgcn_sched_barrier(0);   // pin check AFTER waitcnt (rule #18)
          u32x4 m4 = umax4(umax4(hf[0], hf[1]), umax4(hf[2], hf[3]));
          uint32_t m01 = m4[0] > m4[1] ? m4[0] : m4[1];
          uint32_t m23 = m4[2] > m4[3] ? m4[2] : m4[3];
          uint32_t m = m01 > m23 ? m01 : m23;
          if (__all(m != 0xFFFFFFFFu)) break;
        }
        __builtin_amdgcn_sched_barrier(0);
        // publish to LDS, chunk-swizzled: (batch, cib) -> hlds[batch*128 + (cib^(batch&7))]
        #pragma unroll
        for (int j = 0; j < 4; ++j){
          int cib = pch*4 + j;
          ((u32x4*)hlds)[pbat*128 + (cib ^ (pbat & 7))] = hf[j];
        }
      }
      __syncthreads();   // all chunks in LDS, fenced
      // block 0 read the ENTIRE slot t coherently -> certify (single 4B flag)
      if (bid == 0 && tid == 0) store_coh4(allvis + t, 1u);

      // ---- full-K MFMA: af = h[batch lr][k chunk kk*4+lk] (swizzled read)
      f32x4 a0 = (f32x4){0.f,0.f,0.f,0.f}, a1 = a0;
      #pragma unroll
      for (int kk = 0; kk < 32; kk += 2){
        bf16x8 af0 = *(const bf16x8*)&((const u32x4*)hlds)[lr*128 + (( kk   *4 + lk) ^ (lr & 7))];
        bf16x8 af1 = *(const bf16x8*)&((const u32x4*)hlds)[lr*128 + (((kk+1)*4 + lk) ^ (lr & 7))];
        a0 = __builtin_amdgcn_mfma_f32_16x16x32_bf16(af0, wf[kk  ], a0, 0, 0, 0);
        a1 = __builtin_amdgcn_mfma_f32_16x16x32_bf16(af1, wf[kk+1], a1, 0, 0, 0);
      }
      f32x4 acc = a0 + a1;

      // tanh + transpose via hs2 (C/D: row=(l>>4)*4+r = batch, col=l&15)
      #pragma unroll
      for (int r = 0; r < 4; ++r){
        float hv = tanh_fast(xpreg[r] + acc[r]);
        hs2[(lk*4 + r)*128 + wv*16 + lr] = f2bf(hv);
        if (t == NS-1) hfin[(long)(lk*4 + r) * NH + base + lr] = hv;
      }
      __syncthreads();   // hs2 complete; also closes hlds reuse for t+1

      // coalesced write-through store of the block's 128-col slice of slot t+1
      {
        int row = tid >> 5, ch = tid & 31;     // 16 rows x 32 chunks of 8B
        uint64_t v = *(const uint64_t*)&hs2[row*128 + ch*4];
        char* dst = (char*)hch + ((long)(t+1) * NB + row) * 2048 + bid*256 + ch*8;
        store_coh8(dst, v);
      }
      if (t + 1 < NS){
        #pragma unroll
        for (int r = 0; r < 4; ++r)
          xpreg[r] = xp[((long)(lk*4 + r) * NS + (t+1)) * NH + base + lr];
      }
    }
    asm volatile("s_waitcnt vmcnt(0)" ::: "memory");   // slot-256 stores acked
    __syncthreads();
    if (tid == 0) store_coh4(fin + bid, 1u);
    return;
  }

  // ================= logits path: 2 sub-engines x 256 threads ===============
  int sub = tid >> 8;                      // 0 or 1
  int st  = tid & 255;
  uint16_t* As = (uint16_t*)(smem + sub*16384);          // 8 KB each
  uint16_t* Bs = (uint16_t*)(smem + sub*16384 + 8192);
  int gbid = bid - 8;                      // 0..3999
  int tile = gbid*2 + sub;                 // 0..7999, s-major
  int tm = tile / 250;                     // s-group (8 steps per tile)
  int tn = tile % 250;
  int Mb = tm * 128, Nb = tn * 128;
  int tmmax = (gbid*2 + 1) / 250;          // gate on max of both tiles (uniform)

  if (tmmax < 31){                         // gate: ONE u32 (shared line)
    int hs = tmmax * 8 + 8;
    while (true){
      uint32_t f = load_coh4(allvis + hs);
      asm volatile("s_waitcnt vmcnt(0)" ::: "memory");
      __builtin_amdgcn_sched_barrier(0);
      if (__syncthreads_count(f == 0u) == 0) break;
      __builtin_amdgcn_s_sleep(16);
    }
  } else {                                 // last s-group: 8 per-block finals
    const uint32_t* gp = fin + (tid & 7);
    while (true){
      uint32_t f = load_coh4(gp);
      asm volatile("s_waitcnt vmcnt(0)" ::: "memory");
      __builtin_amdgcn_sched_barrier(0);
      if (__syncthreads_count(f == 0u) == 0) break;
      __builtin_amdgcn_s_sleep(16);
    }
  }

  int wv = st >> 6, l = st & 63;
  int wm = wv >> 1, wn = wv & 1;
  int lr = l & 15, lk = l >> 4;

  int r0 = st >> 2, c0 = st & 3;
  int r1 = r0 + 64;
  // s-major: A row m <-> hchain row m+16 (contiguous)
  const uint16_t* pa0 = hch + (long)(Mb + r0 + 16) * NH + c0*8;
  const uint16_t* pa1 = hch + (long)(Mb + r1 + 16) * NH + c0*8;
  const uint16_t* pb0 = whobf + (long)(Nb + r0) * NH + c0*8;
  const uint16_t* pb1 = whobf + (long)(Nb + r1) * NH + c0*8;
  int da0 = r0*4 + (c0 ^ (r0 & 3));
  int da1 = r1*4 + (c0 ^ (r1 & 3));

  u32x4 ra0 = *(const u32x4*)pa0;
  u32x4 ra1 = *(const u32x4*)pa1;
  u32x4 rb0 = *(const u32x4*)pb0;
  u32x4 rb1 = *(const u32x4*)pb1;

  f32x4 acc[4][4];
  #pragma unroll
  for (int i = 0; i < 4; ++i)
    #pragma unroll
    for (int jj = 0; jj < 4; ++jj) acc[i][jj] = (f32x4){0.f,0.f,0.f,0.f};

  for (int kt = 0; kt < 32; ++kt){
    ((u32x4*)As)[da0] = ra0;
    ((u32x4*)As)[da1] = ra1;
    ((u32x4*)Bs)[da0] = rb0;
    ((u32x4*)Bs)[da1] = rb1;
    __syncthreads();                       // both subs: identical barrier count
    if (kt != 31){
      int off = (kt + 1) * 32;
      ra0 = *(const u32x4*)(pa0 + off);
      ra1 = *(const u32x4*)(pa1 + off);
      rb0 = *(const u32x4*)(pb0 + off);
      rb1 = *(const u32x4*)(pb1 + off);
    }
    bf16x8 af[4], bg_[4];
    #pragma unroll
    for (int i = 0; i < 4; ++i){
      int ra = wm*64 + i*16 + lr;
      int rb = wn*64 + i*16 + lr;
      af[i]  = *(const bf16x8*)&((const u32x4*)As)[ra*4 + (lk ^ (ra & 3))];
      bg_[i] = *(const bf16x8*)&((const u32x4*)Bs)[rb*4 + (lk ^ (rb & 3))];
    }
    #pragma unroll
    for (int i = 0; i < 4; ++i)
      #pragma unroll
      for (int jj = 0; jj < 4; ++jj)
        acc[i][jj] = __builtin_amdgcn_mfma_f32_16x16x32_bf16(af[i], bg_[jj], acc[i][jj], 0, 0, 0);
    __syncthreads();
  }

  #pragma unroll
  for (int jj = 0; jj < 4; ++jj){
    int col = Nb + wn*64 + jj*16 + lr;
    float bias = whob[col];
    #pragma unroll
    for (int i = 0; i < 4; ++i){
      #pragma unroll
      for (int rr = 0; rr < 4; ++rr){
        int m = Mb + wm*64 + i*16 + lk*4 + rr;      // m = s*16 + b
        long orow = (long)((m & 15) * 256 + (m >> 4));
        store_nt4(&out[orow * NV + col], acc[i][jj][rr] + bias);
      }
    }
  }
}

extern "C" void kernel_launch(void* const* d_in, const int* in_sizes, int n_in,
                              void* d_out, int out_size, void* d_ws, size_t ws_size,
                              hipStream_t stream){
  (void)in_sizes; (void)n_in; (void)out_size;
  if (ws_size < (size_t)WS_NEED) return;   // insufficient scratch -> fail loudly

  const int*   ids    = (const int*)  d_in[0];
  const float* hidden = (const float*)d_in[1];
  const float* table  = (const float*)d_in[2];
  const float* wxh    = (const float*)d_in[3];
  const float* bxh    = (const float*)d_in[4];
  const float* whh    = (const float*)d_in[5];
  const float* who    = (const float*)d_in[6];
  const float* whob   = (const float*)d_in[7];

  char* ws = (char*)d_ws;
  float*    xp     = (float*)   (ws + WS_XP);
  uint16_t* hchain = (uint16_t*)(ws + WS_HCH);
  uint16_t* whobf  = (uint16_t*)(ws + WS_WHO);
  uint32_t* allvis = (uint32_t*)(ws + WS_FLG);     // [260]
  uint32_t* fin    = allvis + 260;                 // [8]
  float* out    = (float*)d_out;
  float* hfinal = out + (long)NB * NS * NV;   // 131,072,000

  k_init <<<2048,  256, 0, stream>>>(hidden, hchain, allvis);
  k_cvt  <<<16000, 256, 0, stream>>>(who, (uint32_t*)whobf);
  k_xproj<<<1024,  256, 0, stream>>>(ids, table, wxh, bxh, xp);
  k_fused<<<4008,  512, 0, stream>>>(whh, xp, hchain, whobf, whob,
                                     allvis, fin, out, hfinal);
}